// Round 4
// baseline (61.757 us; speedup 1.0000x reference)
//
#include <hip/hip_runtime.h>
#include <math.h>

#define CC 512
#define HH 256
#define WW 256
#define NT 512            // 8 waves per block
#define NW (NT / 64)      // 8 bands
#define BH (HH / NW)      // 32 rows per band

typedef float f32x4 __attribute__((ext_vector_type(4)));

// DPP move with -inf fill for invalid/masked lanes (old = -inf, bound_ctrl = false)
template<int CTRL, int ROW_MASK>
__device__ __forceinline__ float dpp_ninf(float v) {
    union { float f; int i; } o, s, r;
    o.f = -INFINITY;
    s.f = v;
    r.i = __builtin_amdgcn_update_dpp(o.i, s.i, CTRL, ROW_MASK, 0xF, false);
    return r.f;
}

// 64-lane inclusive max-scan, pure DPP/VALU (verified absmax=0 in rounds 1-3)
__device__ __forceinline__ float wave_incl_max(float v) {
    v = fmaxf(v, dpp_ninf<0x111, 0xF>(v));  // row_shr:1
    v = fmaxf(v, dpp_ninf<0x112, 0xF>(v));  // row_shr:2
    v = fmaxf(v, dpp_ninf<0x114, 0xF>(v));  // row_shr:4
    v = fmaxf(v, dpp_ninf<0x118, 0xF>(v));  // row_shr:8
    v = fmaxf(v, dpp_ninf<0x142, 0xA>(v));  // row_bcast15 -> rows 1,3
    v = fmaxf(v, dpp_ninf<0x143, 0xC>(v));  // row_bcast31 -> rows 2,3
    return v;
}

__device__ __forceinline__ f32x4 fmax4(f32x4 a, f32x4 b) {
    f32x4 r;
    r.x = fmaxf(a.x, b.x);
    r.y = fmaxf(a.y, b.y);
    r.z = fmaxf(a.z, b.z);
    r.w = fmaxf(a.w, b.w);
    return r;
}

__global__ __launch_bounds__(NT) void corner_pool_kernel(const float* __restrict__ x,
                                                         float* __restrict__ out) {
    __shared__ f32x4 colmax[NW][64];   // 8 KiB: per-band column maxima

    const int t    = threadIdx.x;
    const int lane = t & 63;
    const int w    = t >> 6;           // band index
    const int c    = blockIdx.x;

    const float* xc   = x   + (size_t)c * HH * WW;
    float*       oc   = out + (size_t)c * HH * WW;
    const float* band = xc + (size_t)w * BH * WW;   // this wave's 32-row band
    float*       ob   = oc + (size_t)w * BH * WW;

    const f32x4 ninf4 = {-INFINITY, -INFINITY, -INFINITY, -INFINITY};

    // ---- pass 1: per-band column max (lane owns cols 4*lane..4*lane+3) ----
    // last band's colmax is never consumed as a carry -> skip
    if (w < NW - 1) {
        f32x4 m = ninf4;
        #pragma unroll 8
        for (int r = 0; r < BH; ++r) {
            f32x4 v = *(const f32x4*)(band + r * WW + lane * 4);
            m = fmax4(m, v);
        }
        colmax[w][lane] = m;
    }
    __syncthreads();   // the only barrier

    // ---- carry: max of all earlier bands' column maxima ----
    f32x4 cm = ninf4;
    for (int b = 0; b < w; ++b)
        cm = fmax4(cm, colmax[b][lane]);

    // ---- pass 2: column cummax (registers) + DPP row prefix-max, NT store ----
    #pragma unroll 8
    for (int r = 0; r < BH; ++r) {
        f32x4 v = *(const f32x4*)(band + r * WW + lane * 4);   // L2/L3-hot re-read
        cm = fmax4(cm, v);
        float p0 = cm.x;
        float p1 = fmaxf(p0, cm.y);
        float p2 = fmaxf(p1, cm.z);
        float p3 = fmaxf(p2, cm.w);
        float s  = wave_incl_max(p3);
        float e  = dpp_ninf<0x138, 0xF>(s);   // wave_shr:1 -> exclusive prefix
        f32x4 o;
        o.x = 2.0f * fmaxf(e, p0);
        o.y = 2.0f * fmaxf(e, p1);
        o.z = 2.0f * fmaxf(e, p2);
        o.w = 2.0f * fmaxf(e, p3);
        __builtin_nontemporal_store(o, (f32x4*)(ob + (size_t)r * WW + lane * 4));
    }
}

extern "C" void kernel_launch(void* const* d_in, const int* in_sizes, int n_in,
                              void* d_out, int out_size, void* d_ws, size_t ws_size,
                              hipStream_t stream) {
    const float* x = (const float*)d_in[0];
    float* out = (float*)d_out;
    corner_pool_kernel<<<dim3(CC), dim3(NT), 0, stream>>>(x, out);
}

// Round 5
// 46.591 us; speedup vs baseline: 1.3255x; 1.3255x over previous
//
#include <hip/hip_runtime.h>
#include <math.h>

#define CC 512
#define HH 256
#define WW 256
#define NT 1024           // 16 waves per block
#define NW (NT / 64)      // 16 bands
#define BH (HH / NW)      // 16 rows per band

typedef float f32x4 __attribute__((ext_vector_type(4)));

// DPP move with -inf fill for invalid/masked lanes (old = -inf, bound_ctrl = false)
template<int CTRL, int ROW_MASK>
__device__ __forceinline__ float dpp_ninf(float v) {
    union { float f; int i; } o, s, r;
    o.f = -INFINITY;
    s.f = v;
    r.i = __builtin_amdgcn_update_dpp(o.i, s.i, CTRL, ROW_MASK, 0xF, false);
    return r.f;
}

// 64-lane inclusive max-scan, pure DPP/VALU (verified absmax=0 in rounds 1-4)
__device__ __forceinline__ float wave_incl_max(float v) {
    v = fmaxf(v, dpp_ninf<0x111, 0xF>(v));  // row_shr:1
    v = fmaxf(v, dpp_ninf<0x112, 0xF>(v));  // row_shr:2
    v = fmaxf(v, dpp_ninf<0x114, 0xF>(v));  // row_shr:4
    v = fmaxf(v, dpp_ninf<0x118, 0xF>(v));  // row_shr:8
    v = fmaxf(v, dpp_ninf<0x142, 0xA>(v));  // row_bcast15 -> rows 1,3
    v = fmaxf(v, dpp_ninf<0x143, 0xC>(v));  // row_bcast31 -> rows 2,3
    return v;
}

__device__ __forceinline__ f32x4 fmax4(f32x4 a, f32x4 b) {
    f32x4 r;
    r.x = fmaxf(a.x, b.x);
    r.y = fmaxf(a.y, b.y);
    r.z = fmaxf(a.z, b.z);
    r.w = fmaxf(a.w, b.w);
    return r;
}

__global__ __launch_bounds__(NT, 4) void corner_pool_kernel(const float* __restrict__ x,
                                                            float* __restrict__ out) {
    __shared__ f32x4 colmax[NW][64];   // 16 KiB: per-band column maxima

    const int t    = threadIdx.x;
    const int lane = t & 63;
    const int w    = t >> 6;           // band index
    const int c    = blockIdx.x;

    const float* band = x   + (size_t)c * HH * WW + (size_t)w * BH * WW;
    float*       ob   = out + (size_t)c * HH * WW + (size_t)w * BH * WW;

    const f32x4 ninf4 = {-INFINITY, -INFINITY, -INFINITY, -INFINITY};

    // ---- pass 1: load band into registers (single HBM read), band column max ----
    f32x4 v[BH];                       // 64 VGPRs, fully unrolled -> static indices
    f32x4 m = ninf4;
    #pragma unroll
    for (int r = 0; r < BH; ++r) {
        v[r] = *(const f32x4*)(band + r * WW + lane * 4);
        m = fmax4(m, v[r]);
    }
    colmax[w][lane] = m;
    __syncthreads();                   // the only barrier

    // ---- carry: max of all earlier bands' column maxima ----
    f32x4 cm = ninf4;
    for (int b = 0; b < w; ++b)
        cm = fmax4(cm, colmax[b][lane]);

    // ---- pass 2 (registers only): column cummax + DPP row scan, NT store ----
    #pragma unroll
    for (int r = 0; r < BH; ++r) {
        cm = fmax4(cm, v[r]);
        float p0 = cm.x;
        float p1 = fmaxf(p0, cm.y);
        float p2 = fmaxf(p1, cm.z);
        float p3 = fmaxf(p2, cm.w);
        float s  = wave_incl_max(p3);
        float e  = dpp_ninf<0x138, 0xF>(s);   // wave_shr:1 -> exclusive prefix
        f32x4 o;
        o.x = 2.0f * fmaxf(e, p0);
        o.y = 2.0f * fmaxf(e, p1);
        o.z = 2.0f * fmaxf(e, p2);
        o.w = 2.0f * fmaxf(e, p3);
        __builtin_nontemporal_store(o, (f32x4*)(ob + (size_t)r * WW + lane * 4));
    }
}

extern "C" void kernel_launch(void* const* d_in, const int* in_sizes, int n_in,
                              void* d_out, int out_size, void* d_ws, size_t ws_size,
                              hipStream_t stream) {
    const float* x = (const float*)d_in[0];
    float* out = (float*)d_out;
    corner_pool_kernel<<<dim3(CC), dim3(NT), 0, stream>>>(x, out);
}